// Round 10
// baseline (911.942 us; speedup 1.0000x reference)
//
#include <hip/hip_runtime.h>

#define NN 128
#define NITER 300
#define NROUND 5   // R8-proven search: 5 rounds x 4-point, bracket /3125 (~2^11.6)

// ---- DPP wave-64 cross-lane helpers ----
template<int CTRL>
__device__ __forceinline__ float dpp0(float x) {  // invalid lanes contribute 0
  return __int_as_float(__builtin_amdgcn_update_dpp(0, __float_as_int(x), CTRL, 0xF, 0xF, true));
}
template<int CTRL>
__device__ __forceinline__ float dppS(float x) {  // invalid lanes keep self
  int xi = __float_as_int(x);
  return __int_as_float(__builtin_amdgcn_update_dpp(xi, xi, CTRL, 0xF, 0xF, false));
}
__device__ __forceinline__ float bcast63(float x) {
  return __int_as_float(__builtin_amdgcn_readlane(__float_as_int(x), 63));
}
__device__ __forceinline__ float rlane(float x, int l) {   // l literal after unroll
  return __int_as_float(__builtin_amdgcn_readlane(__float_as_int(x), l));
}
__device__ __forceinline__ float wsum(float x) {
  x += dpp0<0x111>(x); x += dpp0<0x112>(x); x += dpp0<0x114>(x);
  x += dpp0<0x118>(x); x += dpp0<0x142>(x); x += dpp0<0x143>(x);
  return bcast63(x);
}
__device__ __forceinline__ void wsum2(float& x, float& y) {  // two interleaved chains
  float a = x, b = y;
  a += dpp0<0x111>(a); b += dpp0<0x111>(b);
  a += dpp0<0x112>(a); b += dpp0<0x112>(b);
  a += dpp0<0x114>(a); b += dpp0<0x114>(b);
  a += dpp0<0x118>(a); b += dpp0<0x118>(b);
  a += dpp0<0x142>(a); b += dpp0<0x142>(b);
  a += dpp0<0x143>(a); b += dpp0<0x143>(b);
  x = bcast63(a); y = bcast63(b);
}
__device__ __forceinline__ void wsum4(float& a, float& b, float& c, float& d) {
  a += dpp0<0x111>(a); b += dpp0<0x111>(b); c += dpp0<0x111>(c); d += dpp0<0x111>(d);
  a += dpp0<0x112>(a); b += dpp0<0x112>(b); c += dpp0<0x112>(c); d += dpp0<0x112>(d);
  a += dpp0<0x114>(a); b += dpp0<0x114>(b); c += dpp0<0x114>(c); d += dpp0<0x114>(d);
  a += dpp0<0x118>(a); b += dpp0<0x118>(b); c += dpp0<0x118>(c); d += dpp0<0x118>(d);
  a += dpp0<0x142>(a); b += dpp0<0x142>(b); c += dpp0<0x142>(c); d += dpp0<0x142>(d);
  a += dpp0<0x143>(a); b += dpp0<0x143>(b); c += dpp0<0x143>(c); d += dpp0<0x143>(d);
  a = bcast63(a); b = bcast63(b); c = bcast63(c); d = bcast63(d);
}
__device__ __forceinline__ void wminmax(float& mn, float& mx) {  // interleaved
  mn = fminf(mn, dppS<0x111>(mn)); mx = fmaxf(mx, dppS<0x111>(mx));
  mn = fminf(mn, dppS<0x112>(mn)); mx = fmaxf(mx, dppS<0x112>(mx));
  mn = fminf(mn, dppS<0x114>(mn)); mx = fmaxf(mx, dppS<0x114>(mx));
  mn = fminf(mn, dppS<0x118>(mn)); mx = fmaxf(mx, dppS<0x118>(mx));
  mn = fminf(mn, dppS<0x142>(mn)); mx = fmaxf(mx, dppS<0x142>(mx));
  mn = fminf(mn, dppS<0x143>(mn)); mx = fmaxf(mx, dppS<0x143>(mx));
  mn = bcast63(mn); mx = bcast63(mx);
}

// TWO WAVES PER SAMPLE: block = 128 threads. Wave w owns Q columns [64w, 64w+64),
// rows {lane, lane+64} -> 128 regs/wave. 1024 blocks -> 2048 waves = 2 waves/SIMD:
// a different sample's wave fills each DPP/barrier stall (R5-R9 were latency-bound
// at 1 wave/SIMD). Both waves run the projection redundantly on identical v
// (both read both partials from LDS in the same order -> bit-identical).
__launch_bounds__(128, 2)   // min 2 waves/EU -> 256-VGPR budget, need ~170
__global__ void markowitz_kernel(const float* __restrict__ rets,
                                 const float* __restrict__ cov,
                                 const float* __restrict__ gam,
                                 const float* __restrict__ alp,
                                 float* __restrict__ out)
{
  __shared__ float part[2][2][NN];   // [parity][wave][row] partial row-sums
  __shared__ float red[2];

  const int b    = blockIdx.x;
  const int t    = threadIdx.x;
  const int lane = t & 63;
  const int wave = t >> 6;           // 0/1 = column half

  const float g   = gam[b];
  const float g2  = g * g;
  const float aab = fabsf(alp[b]);
  const float* cb = cov + (size_t)b * (NN * NN);

  // ---------- build: qA[u] = (C^T C)[lane][64w+u], qB[u] = [64+lane][64w+u] ----------
  float qA[64], qB[64];
  #pragma unroll
  for (int u = 0; u < 64; ++u) { qA[u] = 0.f; qB[u] = 0.f; }

  const float* ap0 = cb + lane;
  const float* ap1 = cb + lane + 64;
  #pragma unroll 2
  for (int k = 0; k < NN; ++k) {
    float a0 = ap0[(size_t)k * NN];      // C[k][lane]      (coalesced)
    float a1 = ap1[(size_t)k * NN];      // C[k][lane+64]
    float av = wave ? a1 : a0;           // lanes hold C[k][64w + laneidx]
    #pragma unroll
    for (int u = 0; u < 64; ++u) {
      float s = rlane(av, u);            // C[k][64w+u]
      qA[u] = fmaf(a0, s, qA[u]);
      qB[u] = fmaf(a1, s, qB[u]);
    }
  }

  // scale by g2, add diagonal (qA diag only in wave0 at u==lane; qB only wave1)
  float ss0 = 0.f, ss1 = 0.f;
  #pragma unroll
  for (int u = 0; u < 64; ++u) {
    float qa = g2 * qA[u]; if (wave == 0 && u == lane) qa += aab;
    float qb = g2 * qB[u]; if (wave == 1 && u == lane) qb += aab;
    qA[u] = qa; qB[u] = qb;
    ss0 = fmaf(qa, qa, ss0);
    ss1 = fmaf(qb, qb, ss1);
  }
  float ssw = wsum(ss0 + ss1);
  if (lane == 0) red[wave] = ssw;
  __syncthreads();
  const float S    = red[0] + red[1];     // same order in both waves
  const float step = 0.5f / sqrtf(S);     // 1/(2||Q||_F)
  const float sc   = 2.f * step;
  #pragma unroll
  for (int u = 0; u < 64; ++u) { qA[u] *= sc; qB[u] *= sc; }   // q = 2*step*Q

  const float r2a = step * rets[b * NN + lane];
  const float r2b = step * rets[b * NN + 64 + lane];

  // ---------- FISTA ----------
  float y0 = 1.f / 128.f, y1 = 1.f / 128.f;   // full y state in BOTH waves
  float w0p = y0, w1p = y1;
  float t_f = 1.f;

  #pragma unroll 1
  for (int it = 0; it < NITER; ++it) {
    const int p = it & 1;
    // half-matvec: rows {lane,lane+64} x own column half; y bcast via readlane
    float yv = wave ? y1 : y0;           // y[64w + laneidx]
    float pA0 = 0.f, pA1 = 0.f, pB0 = 0.f, pB1 = 0.f;
    #pragma unroll
    for (int u = 0; u < 64; u += 2) {
      float s0 = rlane(yv, u);
      float s1 = rlane(yv, u + 1);
      pA0 = fmaf(qA[u],     s0, pA0);
      pA1 = fmaf(qA[u + 1], s1, pA1);
      pB0 = fmaf(qB[u],     s0, pB0);
      pB1 = fmaf(qB[u + 1], s1, pB1);
    }
    part[p][wave][lane]      = pA0 + pA1;
    part[p][wave][64 + lane] = pB0 + pB1;
    __syncthreads();                     // one barrier/iter (parity dbuf)
    float pAs = part[p][0][lane]      + part[p][1][lane];
    float pBs = part[p][0][64 + lane] + part[p][1][64 + lane];
    float v0 = y0 - pAs + r2a;           // v = y - step*grad (identical in both waves)
    float v1 = y1 - pBs + r2b;

    // projection onto {sum w=1, 0<=w<=1} — R8 verbatim
    float mn = fminf(v0, v1), mx = fmaxf(v0, v1);
    wminmax(mn, mx);
    float lo = mn - 1.0f;
    float W  = mx - lo;
    #pragma unroll 1
    for (int r = 0; r < NROUND; ++r) {
      float h  = W * 0.2f;
      float t1v = lo + h, t2v = lo + 2.f*h, t3v = lo + 3.f*h, t4v = lo + 4.f*h;
      float s1 = __builtin_amdgcn_fmed3f(v0 - t1v, 0.f, 1.f)
               + __builtin_amdgcn_fmed3f(v1 - t1v, 0.f, 1.f);
      float s2 = __builtin_amdgcn_fmed3f(v0 - t2v, 0.f, 1.f)
               + __builtin_amdgcn_fmed3f(v1 - t2v, 0.f, 1.f);
      float s3 = __builtin_amdgcn_fmed3f(v0 - t3v, 0.f, 1.f)
               + __builtin_amdgcn_fmed3f(v1 - t3v, 0.f, 1.f);
      float s4 = __builtin_amdgcn_fmed3f(v0 - t4v, 0.f, 1.f)
               + __builtin_amdgcn_fmed3f(v1 - t4v, 0.f, 1.f);
      wsum4(s1, s2, s3, s4);
      float cnt4 = ((s1 > 1.f ? 1.f : 0.f) + (s2 > 1.f ? 1.f : 0.f))
                 + ((s3 > 1.f ? 1.f : 0.f) + (s4 > 1.f ? 1.f : 0.f));
      lo = fmaf(cnt4, h, lo);
      W  = h;
    }
    float tau0 = lo + 0.5f * W;

    // exact tau on the (fixed) active set
    float z0 = v0 - tau0, z1 = v1 - tau0;
    bool f0 = (z0 > 0.f) && (z0 < 1.0f);
    bool f1 = (z1 > 0.f) && (z1 < 1.0f);
    bool cap0 = (z0 >= 1.0f), cap1 = (z1 >= 1.0f);
    float sfv = (f0 ? v0 : 0.f) + (f1 ? v1 : 0.f);
    float cnt = (f0 ? 1.f : 0.f) + (f1 ? 1.f : 0.f)
              + 1024.f * ((cap0 ? 1.f : 0.f) + (cap1 ? 1.f : 0.f));
    wsum2(sfv, cnt);
    float nu    = floorf(cnt * (1.f / 1024.f));
    float nfree = fmaxf(cnt - 1024.f * nu, 1.f);
    float tauf  = (sfv + nu - 1.f) / nfree;
    float w0 = f0 ? (v0 - tauf) : (cap0 ? 1.0f : 0.f);
    float w1 = f1 ? (v1 - tauf) : (cap1 ? 1.0f : 0.f);

    // FISTA momentum
    float tn   = 0.5f * (1.f + sqrtf(1.f + 4.f * t_f * t_f));
    float coef = (t_f - 1.f) / tn;
    y0 = w0 + coef * (w0 - w0p);
    y1 = w1 + coef * (w1 - w1p);
    w0p = w0; w1p = w1;
    t_f = tn;
  }

  if (wave == 0) {
    out[(size_t)b * NN + lane]      = w0p;
    out[(size_t)b * NN + 64 + lane] = w1p;
  }
}

extern "C" void kernel_launch(void* const* d_in, const int* in_sizes, int n_in,
                              void* d_out, int out_size, void* d_ws, size_t ws_size,
                              hipStream_t stream) {
  (void)n_in; (void)d_ws; (void)ws_size; (void)out_size;
  const float* rets = (const float*)d_in[0];
  const float* cov  = (const float*)d_in[1];
  const float* gam  = (const float*)d_in[2];
  const float* alp  = (const float*)d_in[3];
  float* out = (float*)d_out;
  const int B = in_sizes[0] / NN;   // 1024 blocks, 2 waves each
  markowitz_kernel<<<B, 128, 0, stream>>>(rets, cov, gam, alp, out);
}

// Round 11
// 674.592 us; speedup vs baseline: 1.3518x; 1.3518x over previous
//
#include <hip/hip_runtime.h>

#define NN 128
#define NITER 300
#define NROUND 5   // R8-proven search: 5 rounds x 4-point, bracket /3125 (~2^11.6)

// ---- DPP wave-64 cross-lane helpers ----
template<int CTRL>
__device__ __forceinline__ float dpp0(float x) {  // invalid lanes contribute 0
  return __int_as_float(__builtin_amdgcn_update_dpp(0, __float_as_int(x), CTRL, 0xF, 0xF, true));
}
template<int CTRL>
__device__ __forceinline__ float dppS(float x) {  // invalid lanes keep self
  int xi = __float_as_int(x);
  return __int_as_float(__builtin_amdgcn_update_dpp(xi, xi, CTRL, 0xF, 0xF, false));
}
__device__ __forceinline__ float bcast63(float x) {
  return __int_as_float(__builtin_amdgcn_readlane(__float_as_int(x), 63));
}
__device__ __forceinline__ float rlane(float x, int l) {   // l literal after unroll
  return __int_as_float(__builtin_amdgcn_readlane(__float_as_int(x), l));
}
__device__ __forceinline__ float wsum(float x) {
  x += dpp0<0x111>(x); x += dpp0<0x112>(x); x += dpp0<0x114>(x);
  x += dpp0<0x118>(x); x += dpp0<0x142>(x); x += dpp0<0x143>(x);
  return bcast63(x);
}
__device__ __forceinline__ void wsum2(float& x, float& y) {  // two interleaved chains
  float a = x, b = y;
  a += dpp0<0x111>(a); b += dpp0<0x111>(b);
  a += dpp0<0x112>(a); b += dpp0<0x112>(b);
  a += dpp0<0x114>(a); b += dpp0<0x114>(b);
  a += dpp0<0x118>(a); b += dpp0<0x118>(b);
  a += dpp0<0x142>(a); b += dpp0<0x142>(b);
  a += dpp0<0x143>(a); b += dpp0<0x143>(b);
  x = bcast63(a); y = bcast63(b);
}
__device__ __forceinline__ void wsum4(float& a, float& b, float& c, float& d) {
  a += dpp0<0x111>(a); b += dpp0<0x111>(b); c += dpp0<0x111>(c); d += dpp0<0x111>(d);
  a += dpp0<0x112>(a); b += dpp0<0x112>(b); c += dpp0<0x112>(c); d += dpp0<0x112>(d);
  a += dpp0<0x114>(a); b += dpp0<0x114>(b); c += dpp0<0x114>(c); d += dpp0<0x114>(d);
  a += dpp0<0x118>(a); b += dpp0<0x118>(b); c += dpp0<0x118>(c); d += dpp0<0x118>(d);
  a += dpp0<0x142>(a); b += dpp0<0x142>(b); c += dpp0<0x142>(c); d += dpp0<0x142>(d);
  a += dpp0<0x143>(a); b += dpp0<0x143>(b); c += dpp0<0x143>(c); d += dpp0<0x143>(d);
  a = bcast63(a); b = bcast63(b); c = bcast63(c); d = bcast63(d);
}
__device__ __forceinline__ void wminmax(float& mn, float& mx) {  // interleaved
  mn = fminf(mn, dppS<0x111>(mn)); mx = fmaxf(mx, dppS<0x111>(mx));
  mn = fminf(mn, dppS<0x112>(mn)); mx = fmaxf(mx, dppS<0x112>(mx));
  mn = fminf(mn, dppS<0x114>(mn)); mx = fmaxf(mx, dppS<0x114>(mx));
  mn = fminf(mn, dppS<0x118>(mn)); mx = fmaxf(mx, dppS<0x118>(mx));
  mn = fminf(mn, dppS<0x142>(mn)); mx = fmaxf(mx, dppS<0x142>(mx));
  mn = fminf(mn, dppS<0x143>(mn)); mx = fmaxf(mx, dppS<0x143>(mx));
  mn = bcast63(mn); mx = bcast63(mx);
}

// ONE WAVE PER SAMPLE (R8 structure — best at 630 us; R10's 2-wave split paid
// redundant-work > stalls-filled). R11 change: FISTA matvec broadcasts via
// ds_bpermute_b32 (LDS crossbar pipe) instead of v_readlane — removes 128
// VALU insts + their VALU->SGPR->VALU hazards from the hot stream per iter.
__launch_bounds__(64, 1)
__global__ void markowitz_kernel(const float* __restrict__ rets,
                                 const float* __restrict__ cov,
                                 const float* __restrict__ gam,
                                 const float* __restrict__ alp,
                                 float* __restrict__ out)
{
  const int b    = blockIdx.x;
  const int lane = threadIdx.x;          // block = exactly one wave (64)

  const float g   = gam[b];
  const float g2  = g * g;
  const float aab = fabsf(alp[b]);
  const float* cb = cov + (size_t)b * (NN * NN);

  // ---------- build Q = g2*C^T C + aab*I (rows lane / lane+64) ----------
  float accA[NN], accB[NN];
  #pragma unroll
  for (int u = 0; u < NN; ++u) { accA[u] = 0.f; accB[u] = 0.f; }

  const float* ap0 = cb + lane;
  const float* ap1 = cb + lane + 64;
  #pragma unroll 2
  for (int k = 0; k < NN; ++k) {
    float a0 = ap0[(size_t)k * NN];      // C[k][lane]      (coalesced)
    float a1 = ap1[(size_t)k * NN];      // C[k][lane+64]
    #pragma unroll
    for (int u = 0; u < 64; ++u) {
      float s0 = rlane(a0, u);           // C[k][u]
      float s1 = rlane(a1, u);           // C[k][64+u]
      accA[u]      = fmaf(a0, s0, accA[u]);
      accA[64 + u] = fmaf(a0, s1, accA[64 + u]);
      accB[u]      = fmaf(a1, s0, accB[u]);
      accB[64 + u] = fmaf(a1, s1, accB[64 + u]);
    }
  }

  // scale, diagonal, Frobenius^2 (4 partial chains)
  float ss0 = 0.f, ss1 = 0.f, ss2 = 0.f, ss3 = 0.f;
  #pragma unroll
  for (int u = 0; u < NN; ++u) {
    float qa = g2 * accA[u]; if (u == lane)      qa += aab;
    float qb = g2 * accB[u]; if (u == lane + 64) qb += aab;
    accA[u] = qa; accB[u] = qb;
    if (u & 1) { ss0 = fmaf(qa, qa, ss0); ss1 = fmaf(qb, qb, ss1); }
    else       { ss2 = fmaf(qa, qa, ss2); ss3 = fmaf(qb, qb, ss3); }
  }
  const float S    = wsum((ss0 + ss2) + (ss1 + ss3));
  const float step = 0.5f / sqrtf(S);    // 1/(2||Q||_F)
  const float sc   = 2.f * step;
  #pragma unroll
  for (int u = 0; u < NN; ++u) { accA[u] *= sc; accB[u] *= sc; }  // acc = 2*step*Q

  const float r2a = step * rets[b * NN + lane];
  const float r2b = step * rets[b * NN + 64 + lane];

  // ---------- FISTA, fully in-wave ----------
  float y0 = 1.f / 128.f, y1 = 1.f / 128.f;   // y coords (lane, lane+64)
  float w0p = y0, w1p = y1;                   // w_prev
  float t_f = 1.f;

  #pragma unroll 1
  for (int it = 0; it < NITER; ++it) {
    // matvec: broadcasts via ds_bpermute (LDS crossbar, lgkmcnt pipe) — VALU
    // stream keeps only the 256 fma (+ addr bumps). Bit-identical to readlane.
    float pA0 = 0.f, pA1 = 0.f, pB0 = 0.f, pB1 = 0.f;
    int iy0 = __float_as_int(y0);
    int iy1 = __float_as_int(y1);
    int addr = 0;
    #pragma unroll
    for (int u = 0; u < 64; ++u) {
      float t0 = __int_as_float(__builtin_amdgcn_ds_bpermute(addr, iy0));  // y[u]
      float t1 = __int_as_float(__builtin_amdgcn_ds_bpermute(addr, iy1));  // y[64+u]
      addr += 4;
      pA0 = fmaf(accA[u],      t0, pA0);
      pA1 = fmaf(accA[64 + u], t1, pA1);
      pB0 = fmaf(accB[u],      t0, pB0);
      pB1 = fmaf(accB[64 + u], t1, pB1);
    }
    float v0 = y0 - (pA0 + pA1) + r2a;   // v = y - step*grad
    float v1 = y1 - (pB0 + pB1) + r2b;

    // projection onto {sum w=1, 0<=w<=1}: 5 rounds x 4-point bracket search
    float mn = fminf(v0, v1), mx = fmaxf(v0, v1);
    wminmax(mn, mx);
    float lo = mn - 1.0f;
    float W  = mx - lo;
    #pragma unroll 1
    for (int r = 0; r < NROUND; ++r) {
      float h  = W * 0.2f;
      float t1v = lo + h, t2v = lo + 2.f*h, t3v = lo + 3.f*h, t4v = lo + 4.f*h;
      float s1 = __builtin_amdgcn_fmed3f(v0 - t1v, 0.f, 1.f)
               + __builtin_amdgcn_fmed3f(v1 - t1v, 0.f, 1.f);
      float s2 = __builtin_amdgcn_fmed3f(v0 - t2v, 0.f, 1.f)
               + __builtin_amdgcn_fmed3f(v1 - t2v, 0.f, 1.f);
      float s3 = __builtin_amdgcn_fmed3f(v0 - t3v, 0.f, 1.f)
               + __builtin_amdgcn_fmed3f(v1 - t3v, 0.f, 1.f);
      float s4 = __builtin_amdgcn_fmed3f(v0 - t4v, 0.f, 1.f)
               + __builtin_amdgcn_fmed3f(v1 - t4v, 0.f, 1.f);
      wsum4(s1, s2, s3, s4);
      // s monotone decreasing in tau: cnt = #points with s>1 selects sub-interval
      float cnt = ((s1 > 1.f ? 1.f : 0.f) + (s2 > 1.f ? 1.f : 0.f))
                + ((s3 > 1.f ? 1.f : 0.f) + (s4 > 1.f ? 1.f : 0.f));
      lo = fmaf(cnt, h, lo);
      W  = h;
    }
    float tau0 = lo + 0.5f * W;

    // exact tau on the (fixed) active set, then w  (R8 verbatim)
    float z0 = v0 - tau0, z1 = v1 - tau0;
    bool f0 = (z0 > 0.f) && (z0 < 1.0f);
    bool f1 = (z1 > 0.f) && (z1 < 1.0f);
    bool cap0 = (z0 >= 1.0f), cap1 = (z1 >= 1.0f);
    float sfv = (f0 ? v0 : 0.f) + (f1 ? v1 : 0.f);
    float cnt = (f0 ? 1.f : 0.f) + (f1 ? 1.f : 0.f)
              + 1024.f * ((cap0 ? 1.f : 0.f) + (cap1 ? 1.f : 0.f));
    wsum2(sfv, cnt);
    float nu    = floorf(cnt * (1.f / 1024.f));
    float nfree = fmaxf(cnt - 1024.f * nu, 1.f);
    float tauf  = (sfv + nu - 1.f) / nfree;        // exact tau on fixed active set
    float w0 = f0 ? (v0 - tauf) : (cap0 ? 1.0f : 0.f);
    float w1 = f1 ? (v1 - tauf) : (cap1 ? 1.0f : 0.f);

    // FISTA momentum
    float tn   = 0.5f * (1.f + sqrtf(1.f + 4.f * t_f * t_f));
    float coef = (t_f - 1.f) / tn;
    y0 = w0 + coef * (w0 - w0p);
    y1 = w1 + coef * (w1 - w1p);
    w0p = w0; w1p = w1;
    t_f = tn;
  }

  out[(size_t)b * NN + lane]      = w0p;
  out[(size_t)b * NN + 64 + lane] = w1p;
}

extern "C" void kernel_launch(void* const* d_in, const int* in_sizes, int n_in,
                              void* d_out, int out_size, void* d_ws, size_t ws_size,
                              hipStream_t stream) {
  (void)n_in; (void)d_ws; (void)ws_size; (void)out_size;
  const float* rets = (const float*)d_in[0];
  const float* cov  = (const float*)d_in[1];
  const float* gam  = (const float*)d_in[2];
  const float* alp  = (const float*)d_in[3];
  float* out = (float*)d_out;
  const int B = in_sizes[0] / NN;   // 1024 waves, one sample each
  markowitz_kernel<<<B, 64, 0, stream>>>(rets, cov, gam, alp, out);
}